// Round 3
// baseline (16064.470 us; speedup 1.0000x reference)
//
#include <hip/hip_runtime.h>

// Bidirectional "LSTM" (degenerate per reference): fwd = single cell on last
// timestep; bwd = 128-step h-only recurrence (c stays 0 -> f-gate dead).
// R3: ONE fused kernel per step: 64 WGs (BN=96 = 32j x 3 gates, BM=256,
// full K=2048(h)+1024(x) virtual chunk list, no split-K) + in-register
// bias+activation tail + LDS-transpose h-fragment write. No partial buffers,
// no act kernel, no xpart pipeline. Numerics = R1/R2 (3-pass bf16 hi/lo).

#define B_    256
#define S_    128
#define E_    1024
#define H_    2048
#define VOC_  50000

typedef __bf16 bf16;
typedef bf16  bf16x8 __attribute__((ext_vector_type(8)));
typedef float f32x4  __attribute__((ext_vector_type(4)));
typedef float f32x16 __attribute__((ext_vector_type(16)));

typedef const char __attribute__((address_space(1)))* gas1_t;
typedef char       __attribute__((address_space(3)))* las3_t;

// ---------------------------------------------------------------------------
// Weight pack: W[8192,K] f32 -> per (jstrip,chunk) 24KB blocks laid out in the
// exact LDS image the GEMM consumes: [hl][gate][kk][lane][16B].
// gate g in {0,1,2} -> original rows {j, 4096+j, 6144+j} (i, g, o).
// Fragment: lane l holds j=l&31, k = kk*16 + (l>>5)*8 + e  (32x32x16 B-frag).
// ---------------------------------------------------------------------------
__global__ __launch_bounds__(256) void pack_w(const float* __restrict__ W,
                                              char* __restrict__ dst, int nchunks) {
  int p = blockIdx.x * 256 + threadIdx.x;
  int lane = p & 63; p >>= 6;
  int kk   = p & 3;  p >>= 2;
  int g    = p % 3;  p /= 3;
  int hl   = p & 1;  p >>= 1;
  int c    = p % nchunks;
  int jstrip = p / nchunks;
  int K  = nchunks * 64;
  int j  = jstrip * 32 + (lane & 31);
  int k0 = c * 64 + kk * 16 + (lane >> 5) * 8;
  int grow = j + (g == 1 ? 4096 : (g == 2 ? 6144 : 0));
  const float* src = W + (size_t)grow * K + k0;
  f32x4 v0 = *(const f32x4*)src;
  f32x4 v1 = *(const f32x4*)(src + 4);
  float f[8] = {v0[0], v0[1], v0[2], v0[3], v1[0], v1[1], v1[2], v1[3]};
  bf16x8 o;
#pragma unroll
  for (int e = 0; e < 8; ++e) {
    float x = f[e];
    bf16 hb = (bf16)x;
    o[e] = hl ? (bf16)(x - (float)hb) : hb;
  }
  size_t off = (size_t)(jstrip * nchunks + c) * 24576
             + (size_t)((hl * 3 + g) * 4 + kk) * 1024 + lane * 16;
  *(bf16x8*)(dst + off) = o;
}

// Bias pack: B3[n*96 + g*32 + j] = b_ih[grow] + b_hh[grow], matching the
// fused kernel's per-WG column layout.
__global__ __launch_bounds__(256) void pack_bias(const float* __restrict__ bib,
                                                 const float* __restrict__ bhb,
                                                 const float* __restrict__ bif,
                                                 const float* __restrict__ bhf,
                                                 float* __restrict__ B3B,
                                                 float* __restrict__ B3F) {
  int t = blockIdx.x * 256 + threadIdx.x;       // 2*6144 = 12288
  int which = t / 6144;
  int r = t % 6144;
  int n = r / 96, q = r % 96, g = q >> 5, j = q & 31;
  int grow = n * 32 + j + (g == 1 ? 4096 : (g == 2 ? 6144 : 0));
  if (which == 0) B3B[r] = bib[grow] + bhb[grow];
  else            B3F[r] = bif[grow] + bhf[grow];
}

// ---------------------------------------------------------------------------
// Embedding gather into time-REVERSED, MFMA-A-fragment-swizzled hi/lo bf16.
// A layout: addr(b,k) = ((k>>4)*8 + (b>>5))*1024 + ((b&31) + 32*((k>>3)&1))*16
//           + (k&7)*2   -> wave frag load = one contiguous 1KB dwordx4.
// Xr[t] = embeds[:, S-1-t]; Xr[0] also serves the forward cell.
// ---------------------------------------------------------------------------
__global__ __launch_bounds__(256) void gather_k(const int* __restrict__ inputs,
                                                const float* __restrict__ emb,
                                                char* __restrict__ XH,
                                                char* __restrict__ XL) {
  int p = blockIdx.x * 256 + threadIdx.x;       // 128*8*64*64 = 4,194,304
  int l   = p & 63; p >>= 6;
  int k16 = p & 63; p >>= 6;
  int b32 = p & 7;  p >>= 3;
  int t   = p;                                   // 0..127
  int b  = b32 * 32 + (l & 31);
  int e0 = k16 * 16 + (l >> 5) * 8;
  int s  = (S_ - 1) - t;
  int iv = inputs[b * S_ + s];
  if ((unsigned)iv >= (unsigned)VOC_) iv = 0;
  const float* src = emb + (size_t)iv * E_ + e0;
  f32x4 v0 = *(const f32x4*)src;
  f32x4 v1 = *(const f32x4*)(src + 4);
  float f[8] = {v0[0], v0[1], v0[2], v0[3], v1[0], v1[1], v1[2], v1[3]};
  bf16x8 vh, vl;
#pragma unroll
  for (int e = 0; e < 8; ++e) {
    bf16 hb = (bf16)f[e];
    vh[e] = hb;
    vl[e] = (bf16)(f[e] - (float)hb);
  }
  size_t off = (size_t)t * 524288 + (size_t)(k16 * 8 + b32) * 1024 + l * 16;
  *(bf16x8*)(XH + off) = vh;
  *(bf16x8*)(XL + off) = vl;
}

// ---------------------------------------------------------------------------
__device__ __forceinline__ float sig_(float x) {
  x = fminf(fmaxf(x, -30.f), 30.f);
  return 1.f / (1.f + __expf(-x));
}
__device__ __forceinline__ float tanh_(float x) {
  x = fminf(fmaxf(x, -15.f), 15.f);
  float e = __expf(2.f * x);
  return (e - 1.f) / (e + 1.f);
}

// ---------------------------------------------------------------------------
// Fully-fused step: grid 64 (one WG per 32-j strip), 512 thr (8 waves).
// Wave = 32m x 96n (3 accs), WG = 256m x 96n. K list = nHc h-chunks (K=64
// each, A = h frags) then nXc x-chunks (A = x frags). Weights staged to LDS
// dbuf via global_load_lds; A direct-to-reg. Tail: bias + LSTM act (c==0),
// LDS-transpose, write next-h bf16 hi/lo frags and/or f32 rows of d_out.
// ---------------------------------------------------------------------------
__global__ __launch_bounds__(512, 1) void fused_step(
    const char* __restrict__ hH, const char* __restrict__ hL, int nHc,
    const char* __restrict__ xH, const char* __restrict__ xL, int nXc,
    const char* __restrict__ Wh, const char* __restrict__ Wx,
    const float* __restrict__ bias3,
    char* __restrict__ hOutH, char* __restrict__ hOutL,
    float* __restrict__ out, int outcol) {
  __shared__ __attribute__((aligned(16))) char sm[49152];
  const int n = blockIdx.x;                      // j-strip 0..63
  const int tid = threadIdx.x;
  const int wid = tid >> 6, lane = tid & 63;
  const int nc = nHc + nXc;

  f32x16 acc[3] = {};

  auto stage = [&](int c, int buf) {
    const char* src = (c < nHc) ? (Wh + (size_t)(n * nHc + c) * 24576)
                                : (Wx + (size_t)(n * nXc + (c - nHc)) * 24576);
#pragma unroll
    for (int i = 0; i < 3; ++i) {
      int off = (i * 8 + wid) * 1024;            // wave-uniform LDS base
      __builtin_amdgcn_global_load_lds((gas1_t)(src + off + lane * 16),
                                       (las3_t)(sm + buf * 24576 + off), 16, 0, 0);
    }
  };

  auto compute = [&](int c, int buf) {
    const char *aH, *aL;
    int kb;
    if (c < nHc) { aH = hH; aL = hL; kb = c * 4; }
    else         { aH = xH; aL = xL; kb = (c - nHc) * 4; }
    const char* bs = sm + buf * 24576;
#pragma unroll
    for (int kk = 0; kk < 4; ++kk) {
      const size_t aoff = (size_t)((kb + kk) * 8 + wid) * 1024 + lane * 16;
      bf16x8 AH = *(const bf16x8*)(aH + aoff);
      bf16x8 AL = *(const bf16x8*)(aL + aoff);
#pragma unroll
      for (int g = 0; g < 3; ++g) {
        bf16x8 BH = *(const bf16x8*)(bs + (size_t)(g * 4 + kk) * 1024 + lane * 16);
        bf16x8 BL = *(const bf16x8*)(bs + (size_t)((g + 3) * 4 + kk) * 1024 + lane * 16);
        acc[g] = __builtin_amdgcn_mfma_f32_32x32x16_bf16(AH, BH, acc[g], 0, 0, 0);
        acc[g] = __builtin_amdgcn_mfma_f32_32x32x16_bf16(AL, BH, acc[g], 0, 0, 0);
        acc[g] = __builtin_amdgcn_mfma_f32_32x32x16_bf16(AH, BL, acc[g], 0, 0, 0);
      }
    }
  };

  stage(0, 0);
  __syncthreads();
  for (int c = 0; c < nc; ++c) {
    if (c + 1 < nc) stage(c + 1, (c + 1) & 1);
    compute(c, c & 1);
    __syncthreads();
  }

  // ---- fused activation tail ----
  // C/D 32x32 layout: col = lane&31, row = (r&3) + 8*(r>>2) + 4*(lane>>5)
  const int j = lane & 31;
  const float bi = bias3[n * 96 + j];
  const float bg = bias3[n * 96 + 32 + j];
  const float bo = bias3[n * 96 + 64 + j];
  float hv[16];
#pragma unroll
  for (int r = 0; r < 16; ++r)
    hv[r] = sig_(acc[2][r] + bo) * tanh_(sig_(acc[0][r] + bi) * tanh_(acc[1][r] + bg));

  if (out) {
#pragma unroll
    for (int r = 0; r < 16; ++r) {
      int row = (r & 3) + ((r >> 2) << 3) + ((lane >> 5) << 2);
      out[(size_t)(wid * 32 + row) * 4096 + outcol + n * 32 + j] = hv[r];
    }
  }

  if (hOutH) {
    // per-wave 32x32 transpose via LDS (rows padded to 36 floats for 16B
    // alignment), then write A-fragment hi/lo: one bf16x8 per (k16-half).
    float* tp = (float*)sm + (size_t)wid * 1152;  // 32 * 36 floats = 4608B/wave
#pragma unroll
    for (int r = 0; r < 16; ++r) {
      int row = (r & 3) + ((r >> 2) << 3) + ((lane >> 5) << 2);
      tp[row * 36 + j] = hv[r];
    }
    __syncthreads();
#pragma unroll
    for (int s = 0; s < 2; ++s) {
      const float* rp = tp + (lane & 31) * 36 + s * 16 + (lane >> 5) * 8;
      f32x4 v0 = *(const f32x4*)rp;
      f32x4 v1 = *(const f32x4*)(rp + 4);
      float f[8] = {v0[0], v0[1], v0[2], v0[3], v1[0], v1[1], v1[2], v1[3]};
      bf16x8 vh, vl;
#pragma unroll
      for (int e = 0; e < 8; ++e) {
        bf16 hb = (bf16)f[e];
        vh[e] = hb;
        vl[e] = (bf16)(f[e] - (float)hb);
      }
      size_t off = (size_t)((n * 2 + s) * 8 + wid) * 1024 + lane * 16;
      *(bf16x8*)(hOutH + off) = vh;
      *(bf16x8*)(hOutL + off) = vl;
    }
  }
}

// ---------------------------------------------------------------------------
extern "C" void kernel_launch(void* const* d_in, const int* in_sizes, int n_in,
                              void* d_out, int out_size, void* d_ws, size_t ws_size,
                              hipStream_t stream) {
  const int*   inputs = (const int*)d_in[0];
  const float* embed  = (const float*)d_in[1];
  const float* Wihf   = (const float*)d_in[2];
  // d_in[3] = W_hh_f: unused (multiplied by zero state in reference)
  const float* bihf   = (const float*)d_in[4];
  const float* bhhf   = (const float*)d_in[5];
  const float* Wihb   = (const float*)d_in[6];
  const float* Whhb   = (const float*)d_in[7];
  const float* bihb   = (const float*)d_in[8];
  const float* bhhb   = (const float*)d_in[9];
  float* out = (float*)d_out;
  char*  ws  = (char*)d_ws;

  size_t o = 0;
  char*  WHHp  = ws + o; o += 50331648;           // 64 jstrips x 32 chunks x 24KB
  char*  WIHBp = ws + o; o += 25165824;           // 64 x 16 x 24KB
  char*  WIHFp = ws + o; o += 25165824;           // 64 x 16 x 24KB
  char*  XRH   = ws + o; o += 67108864;           // 128 t x 512KB
  char*  XRL   = ws + o; o += 67108864;
  char*  HB    = ws + o; o += 4194304;            // h frags: hi0, lo0, hi1, lo1
  float* B3B   = (float*)(ws + o); o += 24576;
  float* B3F   = (float*)(ws + o); o += 24576;
  // total ~239 MB (fits L3 alongside outputs)

  hipMemsetAsync(HB, 0, 4194304, stream);         // h(-1) = 0 (hi & lo frags)

  pack_w<<<12288, 256, 0, stream>>>(Whhb, WHHp, 32);
  pack_w<<<6144, 256, 0, stream>>>(Wihb, WIHBp, 16);
  pack_w<<<6144, 256, 0, stream>>>(Wihf, WIHFp, 16);
  pack_bias<<<48, 256, 0, stream>>>(bihb, bhhb, bihf, bhhf, B3B, B3F);
  gather_k<<<16384, 256, 0, stream>>>(inputs, embed, XRH, XRL);

  // forward cell (h=c=0): gates = x(last)@Wihf + biasF -> d_out[:, 0:2048]
  fused_step<<<64, 512, 0, stream>>>(nullptr, nullptr, 0, XRH, XRL, 16,
                                     nullptr, WIHFp, B3F,
                                     nullptr, nullptr, out, 0);

  char* hHi[2] = {HB, HB + 2097152};
  char* hLo[2] = {HB + 1048576, HB + 3145728};

  for (int t = 0; t < S_; ++t) {
    bool last = (t == S_ - 1);
    fused_step<<<64, 512, 0, stream>>>(
        hHi[t & 1], hLo[t & 1], 32,
        XRH + (size_t)t * 524288, XRL + (size_t)t * 524288, 16,
        WHHp, WIHBp, B3B,
        last ? nullptr : hHi[(t & 1) ^ 1],
        last ? nullptr : hLo[(t & 1) ^ 1],
        last ? out : nullptr, 2048);
  }
}